// Round 5
// baseline (620.250 us; speedup 1.0000x reference)
//
#include <hip/hip_runtime.h>
#include <stdint.h>

// Correlation1dCost: out[b,d,y,x] = leaky_relu_0.1( sum_c f1[b,c,y,x]*f2[b,c,y,x+d-47] )
// B=8, C=128, H=128, W=256, ND=48. Zero contribution where x+d-47 < 0.
//
// R9: occupancy + f1-latency fix. R8 (DMA staging, spill-free) measured
// VGPR=132 -- 4 over the 128 cliff -> 2 waves/SIMD (occupancy 10.7%), and
// per-channel time ~1160cy vs 96cy FMA issue: the f1 global load (cold HBM,
// ~900cy) was prefetched only 1 channel (~190cy) ahead. R9:
//  (a) __launch_bounds__(256,4): cap VGPR at 128 -> 4 waves/SIMD, 4 blk/CU.
//  (b) f1 prefetch ring depth 4 (named av0..av3, reloads inside a x4-
//      unrolled channel loop, every index compile-time). Ring crosses tile
//      boundaries via f1's linear c-stride; last tile redirects reloads to
//      in-bounds rows (harmless redundant loads) instead of branching.
//  (c) barrier moved to TOP of tile body (drains prev tile's DMA + the
//      av preloads issued ~400cy earlier); last tile needs no barrier.
// Register audit: acc 48 + qA/qB 32 + av 16 + addr ~15 = ~111 < 128.

typedef float f32x4 __attribute__((ext_vector_type(4)));

#define Bn 8
#define Cn 128
#define Hn 128
#define Wn 256
#define ND 48
#define F2Q 76           // float4s per s2 row: 12 pad (words -48..-1) + 64 data
#define ROWB (F2Q * 16)  // 1216 B per channel row
#define CC 16            // channels staged per tile
#define NIT (Cn / CC)    // 8 tiles
#define TD 12            // d's per thread
#define BUFB (CC * ROWB) // 19456 B per LDS buffer

__device__ __forceinline__ unsigned lds_off(const void* p) {
    return (unsigned)(uintptr_t)p;
}

// 4 contiguous b128 reads, NO waitcnt, NO memory clobber (ordering vs
// barriers preserved by volatile program order).
#define DS_READ4(q0, q1, q2, q3, off)                                   \
    asm volatile("ds_read_b128 %0, %4\n\t"                              \
                 "ds_read_b128 %1, %4 offset:16\n\t"                    \
                 "ds_read_b128 %2, %4 offset:32\n\t"                    \
                 "ds_read_b128 %3, %4 offset:48"                        \
                 : "=&v"(q0), "=&v"(q1), "=&v"(q2), "=&v"(q3)           \
                 : "v"(off))

// Counted wait tied to the registers it guards ("+v" makes every later
// use of q depend on this asm -> FMAs cannot be hoisted above the wait).
#define WAITQ(q0, q1, q2, q3, n)                                        \
    asm volatile("s_waitcnt lgkmcnt(" #n ")"                            \
                 : "+v"(q0), "+v"(q1), "+v"(q2), "+v"(q3))

__device__ __forceinline__ void lds_write_b128(unsigned off, f32x4 v) {
    asm volatile("ds_write_b128 %0, %1" :: "v"(off), "v"(v) : "memory");
}

// Direct HBM->LDS DMA, 16B per lane. Dest = wave-uniform base + lane*16.
__device__ __forceinline__ void gload_lds16(const float* g, char* lds) {
    __builtin_amdgcn_global_load_lds(
        (const __attribute__((address_space(1))) void*)g,
        (__attribute__((address_space(3))) void*)lds,
        16, 0, 0);
}

// 48 FMAs for one channel. qq[] has only compile-time indices.
#define FMA_CH(av, p0, p1, p2, p3)                                      \
    do {                                                                \
        const float a0 = (av)[0], a1 = (av)[1], a2 = (av)[2], a3 = (av)[3]; \
        float qq[16] = {(p0)[0], (p0)[1], (p0)[2], (p0)[3],             \
                        (p1)[0], (p1)[1], (p1)[2], (p1)[3],             \
                        (p2)[0], (p2)[1], (p2)[2], (p2)[3],             \
                        (p3)[0], (p3)[1], (p3)[2], (p3)[3]};            \
        _Pragma("unroll")                                               \
        for (int dr = 0; dr < TD; ++dr) {                               \
            acc[0][dr] += a0 * qq[dr + 1];                              \
            acc[1][dr] += a1 * qq[dr + 2];                              \
            acc[2][dr] += a2 * qq[dr + 3];                              \
            acc[3][dr] += a3 * qq[dr + 4];                              \
        }                                                               \
    } while (0)

__global__ __launch_bounds__(256, 4)
void corr1d_kernel(const float* __restrict__ f1,
                   const float* __restrict__ f2,
                   float* __restrict__ out)
{
    __shared__ f32x4 s2v[2][CC][F2Q];   // 38912 B -> 4 blocks/CU by LDS

    const int y   = blockIdx.x;      // 0..127
    const int b   = blockIdx.y;      // 0..7
    const int tid = threadIdx.x;
    const int i   = tid & 63;        // x-group: x = 4*i .. 4*i+3
    const int j   = tid >> 6;        // d-group: d = 12*j .. 12*j+11

    char* s2c = (char*)&s2v[0][0][0];
    const unsigned s2b   = lds_off(s2c);
    const unsigned offq0 = s2b + (unsigned)((i + 3 * j) * 16);  // q window base

    const size_t chw = (size_t)Hn * Wn;
    const float* f1base = f1 + ((size_t)b * Cn * Hn + y) * Wn;
    const float* f2base = f2 + ((size_t)b * Cn * Hn + y) * Wn;

    const int sp = tid & 63;         // lane id; data word 4*sp of the row

    // ---- zero the always-zero pad region of BOTH buffers once ----
    if ((tid & 15) < 12) {
        f32x4 z = {0.f, 0.f, 0.f, 0.f};
        unsigned zoff = s2b + (unsigned)(((tid >> 4) * F2Q + (tid & 15)) * 16);
        lds_write_b128(zoff, z);
        lds_write_b128(zoff + BUFB, z);
    }

    float acc[4][TD];
    #pragma unroll
    for (int xr = 0; xr < 4; ++xr)
        #pragma unroll
        for (int dr = 0; dr < TD; ++dr) acc[xr][dr] = 0.f;

    // ---- stage tile 0 into buffer 0 (async DMA) ----
    #pragma unroll
    for (int t = 0; t < 4; ++t) {
        const int r = j + 4 * t;     // wave-uniform row
        gload_lds16(f2base + (size_t)r * chw + sp * 4,
                    s2c + (size_t)(r * F2Q + 12 + sp) * 16);
    }

    // ---- preload f1 ring: channels 0..3 ----
    const float* f1q = f1base + i * 4;
    f32x4 av0 = *(const f32x4*)(f1q + 0 * chw);
    f32x4 av1 = *(const f32x4*)(f1q + 1 * chw);
    f32x4 av2 = *(const f32x4*)(f1q + 2 * chw);
    f32x4 av3 = *(const f32x4*)(f1q + 3 * chw);

    f32x4 qA0, qA1, qA2, qA3, qB0, qB1, qB2, qB3;

    for (int it = 0; it < NIT; ++it) {
        const unsigned pb  = (unsigned)(it & 1) * BUFB;   // read buffer base
        const unsigned pbn = BUFB - pb;                    // write buffer base

        // barrier at tile top: drains tile-it DMA (vmcnt 0) + av preloads,
        // and seals all waves' reads of buf[pbn] from tile it-1.
        __syncthreads();

        // issue next tile's DMA now; lands any time before the next barrier.
        if (it + 1 < NIT) {
            #pragma unroll
            for (int t = 0; t < 4; ++t) {
                const int r = j + 4 * t;
                gload_lds16(f2base + (size_t)((it + 1) * CC + r) * chw + sp * 4,
                            s2c + pbn + (size_t)(r * F2Q + 12 + sp) * 16);
            }
        }

        const float* f1p = f1base + (size_t)(it * CC) * chw + i * 4;
        // ring reloads at cc=12 target channels 16..19 (next tile). On the
        // last tile redirect 4*chw back -> re-reads ch 12..15 (in bounds,
        // values unused). Uniform select, no divergence.
        const float* f1n = (it + 1 < NIT) ? f1p : (f1p - 4 * chw);
        const unsigned roff = offq0 + pb;

        DS_READ4(qA0, qA1, qA2, qA3, roff);

        #pragma unroll
        for (int cc = 0; cc < CC; cc += 4) {
            // ch cc (q in A)
            DS_READ4(qB0, qB1, qB2, qB3, roff + (unsigned)((cc + 1) * ROWB));
            WAITQ(qA0, qA1, qA2, qA3, 4);
            FMA_CH(av0, qA0, qA1, qA2, qA3);
            av0 = *(const f32x4*)((cc + 4 < CC ? f1p : f1n) + (size_t)(cc + 4) * chw);

            // ch cc+1 (q in B)
            DS_READ4(qA0, qA1, qA2, qA3, roff + (unsigned)((cc + 2) * ROWB));
            WAITQ(qB0, qB1, qB2, qB3, 4);
            FMA_CH(av1, qB0, qB1, qB2, qB3);
            av1 = *(const f32x4*)((cc + 5 < CC ? f1p : f1n) + (size_t)(cc + 5) * chw);

            // ch cc+2 (q in A)
            DS_READ4(qB0, qB1, qB2, qB3, roff + (unsigned)((cc + 3) * ROWB));
            WAITQ(qA0, qA1, qA2, qA3, 4);
            FMA_CH(av2, qA0, qA1, qA2, qA3);
            av2 = *(const f32x4*)((cc + 6 < CC ? f1p : f1n) + (size_t)(cc + 6) * chw);

            // ch cc+3 (q in B); prefetch next group's A-read if within tile
            if (cc + 4 < CC) {
                DS_READ4(qA0, qA1, qA2, qA3, roff + (unsigned)((cc + 4) * ROWB));
                WAITQ(qB0, qB1, qB2, qB3, 4);
            } else {
                WAITQ(qB0, qB1, qB2, qB3, 0);   // drain: tile's LDS reads done
            }
            FMA_CH(av3, qB0, qB1, qB2, qB3);
            av3 = *(const f32x4*)((cc + 7 < CC ? f1p : f1n) + (size_t)(cc + 7) * chw);
        }
    }

    // ---- epilogue: leaky_relu + float4 stores (contiguous per wave) ----
    #pragma unroll
    for (int dr = 0; dr < TD; ++dr) {
        int d = j * TD + dr;
        float vx[4];
        #pragma unroll
        for (int xr = 0; xr < 4; ++xr) {
            float t = acc[xr][dr];
            vx[xr] = t >= 0.f ? t : 0.1f * t;
        }
        float4 v = make_float4(vx[0], vx[1], vx[2], vx[3]);
        *(float4*)(out + (((size_t)(b * ND + d) * Hn + y) * Wn + i * 4)) = v;
    }
}

extern "C" void kernel_launch(void* const* d_in, const int* in_sizes, int n_in,
                              void* d_out, int out_size, void* d_ws, size_t ws_size,
                              hipStream_t stream) {
    const float* feat1 = (const float*)d_in[0];
    const float* feat2 = (const float*)d_in[1];
    float* out = (float*)d_out;
    dim3 grid(Hn, Bn);   // blockIdx.x = y, blockIdx.y = b
    dim3 block(256);
    corr1d_kernel<<<grid, block, 0, stream>>>(feat1, feat2, out);
}

// Round 8
// 291.426 us; speedup vs baseline: 2.1283x; 2.1283x over previous
//
#include <hip/hip_runtime.h>
#include <stdint.h>

// Correlation1dCost: out[b,d,y,x] = leaky_relu_0.1( sum_c f1[b,c,y,x]*f2[b,c,y,x+d-47] )
// B=8, C=128, H=128, W=256, ND=48. Zero contribution where x+d-47 < 0.
//
// R12: R10's theory, minus its only novel construct. R10/R11 both died at
// container level (2x). Can't distinguish infra vs kernel-triggered, so
// this round removes readfirstlane (the one element never yet run on HW)
// and keeps the two proven levers:
//  (a) f1 addressed as UNIFORM channel pointer (SGPR base) + i*16B voffset
//      -- removes the divergent 64b f1 pointer chains that made R8 132 VGPR
//      (4 over the cliff -> 2 waves/SIMD, occupancy 10.7%).
//  (b) amdgpu_waves_per_eu(2,4): session-proven cap at 128 VGPR (R6),
//      unlike min-occupancy hints which collapse the allocator to 64 and
//      spill GBs (R5: launch_bounds(,4)-equivalent, R9: same).
// DMA staging addressing is bit-identical to R8 (ran, passed, 124us).
// Register audit: acc 48 + qA/qB 32 + av 8 + addr ~15 = ~105 < 128.
// Target: 4 waves/SIMD, 4 blocks/CU, grid 1024 fully resident.

typedef float f32x4 __attribute__((ext_vector_type(4)));

#define Bn 8
#define Cn 128
#define Hn 128
#define Wn 256
#define ND 48
#define F2Q 76           // float4s per s2 row: 12 pad (words -48..-1) + 64 data
#define ROWB (F2Q * 16)  // 1216 B per channel row
#define CC 16            // channels staged per tile
#define NIT (Cn / CC)    // 8 tiles
#define TD 12            // d's per thread
#define BUFB (CC * ROWB) // 19456 B per LDS buffer

__device__ __forceinline__ unsigned lds_off(const void* p) {
    return (unsigned)(uintptr_t)p;
}

// 4 contiguous b128 reads, NO waitcnt, NO memory clobber (ordering vs
// barriers preserved by volatile program order).
#define DS_READ4(q0, q1, q2, q3, off)                                   \
    asm volatile("ds_read_b128 %0, %4\n\t"                              \
                 "ds_read_b128 %1, %4 offset:16\n\t"                    \
                 "ds_read_b128 %2, %4 offset:32\n\t"                    \
                 "ds_read_b128 %3, %4 offset:48"                        \
                 : "=&v"(q0), "=&v"(q1), "=&v"(q2), "=&v"(q3)           \
                 : "v"(off))

// Counted wait tied to the registers it guards ("+v" makes every later
// use of q depend on this asm -> FMAs cannot be hoisted above the wait).
#define WAITQ(q0, q1, q2, q3, n)                                        \
    asm volatile("s_waitcnt lgkmcnt(" #n ")"                            \
                 : "+v"(q0), "+v"(q1), "+v"(q2), "+v"(q3))

__device__ __forceinline__ void lds_write_b128(unsigned off, f32x4 v) {
    asm volatile("ds_write_b128 %0, %1" :: "v"(off), "v"(v) : "memory");
}

// Direct HBM->LDS DMA, 16B per lane. LDS dest = wave-uniform base + lane*16
// (lane sp's dest component sp*16 == lane*16, so layout matches HW).
// This exact addressing form ran and passed in R8.
__device__ __forceinline__ void gload_lds16(const float* g, char* lds) {
    __builtin_amdgcn_global_load_lds(
        (const __attribute__((address_space(1))) void*)g,
        (__attribute__((address_space(3))) void*)lds,
        16, 0, 0);
}

// 48 FMAs for one channel. qq[] has only compile-time indices.
#define FMA_CH(av, p0, p1, p2, p3)                                      \
    do {                                                                \
        const float a0 = (av)[0], a1 = (av)[1], a2 = (av)[2], a3 = (av)[3]; \
        float qq[16] = {(p0)[0], (p0)[1], (p0)[2], (p0)[3],             \
                        (p1)[0], (p1)[1], (p1)[2], (p1)[3],             \
                        (p2)[0], (p2)[1], (p2)[2], (p2)[3],             \
                        (p3)[0], (p3)[1], (p3)[2], (p3)[3]};            \
        _Pragma("unroll")                                               \
        for (int dr = 0; dr < TD; ++dr) {                               \
            acc[0][dr] += a0 * qq[dr + 1];                              \
            acc[1][dr] += a1 * qq[dr + 2];                              \
            acc[2][dr] += a2 * qq[dr + 3];                              \
            acc[3][dr] += a3 * qq[dr + 4];                              \
        }                                                               \
    } while (0)

__global__ __launch_bounds__(256)
__attribute__((amdgpu_waves_per_eu(2, 4)))
void corr1d_kernel(const float* __restrict__ f1,
                   const float* __restrict__ f2,
                   float* __restrict__ out)
{
    __shared__ f32x4 s2v[2][CC][F2Q];   // 38912 B -> 4 blocks/CU by LDS

    const int y   = blockIdx.x;      // 0..127
    const int b   = blockIdx.y;      // 0..7
    const int tid = threadIdx.x;
    const int i   = tid & 63;        // x-group: x = 4*i .. 4*i+3
    const int j   = tid >> 6;        // d-group: d = 12*j .. 12*j+11

    char* s2c = (char*)&s2v[0][0][0];
    const unsigned s2b   = lds_off(s2c);
    const unsigned offq0 = s2b + (unsigned)((i + 3 * j) * 16);  // q window base

    const size_t chw = (size_t)Hn * Wn;
    const float* f1base = f1 + ((size_t)b * Cn * Hn + y) * Wn;
    const float* f2base = f2 + ((size_t)b * Cn * Hn + y) * Wn;

    const int sp  = tid & 63;        // lane id; data word 4*sp of the row
    const int i4  = i * 4;           // f1 voffset in floats (i*16 bytes)

    // ---- zero the always-zero pad region of BOTH buffers once ----
    if ((tid & 15) < 12) {
        f32x4 z = {0.f, 0.f, 0.f, 0.f};
        unsigned zoff = s2b + (unsigned)(((tid >> 4) * F2Q + (tid & 15)) * 16);
        lds_write_b128(zoff, z);
        lds_write_b128(zoff + BUFB, z);
    }

    float acc[4][TD];
    #pragma unroll
    for (int xr = 0; xr < 4; ++xr)
        #pragma unroll
        for (int dr = 0; dr < TD; ++dr) acc[xr][dr] = 0.f;

    // ---- stage tile 0 into buffer 0 (async DMA); R8-identical form ----
    #pragma unroll
    for (int t = 0; t < 4; ++t) {
        const int r = j + 4 * t;     // wave-uniform row
        gload_lds16(f2base + (size_t)r * chw + sp * 4,
                    s2c + (size_t)(r * F2Q + 12 + sp) * 16);
    }
    __syncthreads();                 // drains vmcnt(0): tile 0 resident

    for (int it = 0; it < NIT; ++it) {
        const unsigned pb  = (unsigned)(it & 1) * BUFB;   // read buffer base
        const unsigned pbn = BUFB - pb;                    // write buffer base

        // issue next tile's DMA now; lands any time before the barrier.
        // buf[pbn] was last READ in tile it-1, all waves past that barrier.
        if (it + 1 < NIT) {
            #pragma unroll
            for (int t = 0; t < 4; ++t) {
                const int r = j + 4 * t;
                gload_lds16(f2base + (size_t)((it + 1) * CC + r) * chw + sp * 4,
                            s2c + pbn + (size_t)(r * F2Q + 12 + sp) * 16);
            }
        }

        // ---- compute 16 channels, reads pipelined 1 channel deep,
        //      hand-unrolled x2 with NAMED register sets (no runtime idx).
        //      f1 addressed as uniform channel pointer + i*16B voffset. ----
        const float* f1t = f1base + (size_t)(it * CC) * chw;  // uniform (SGPR)
        const unsigned roff = offq0 + pb;

        f32x4 qA0, qA1, qA2, qA3, qB0, qB1, qB2, qB3;
        f32x4 avA, avB;
        DS_READ4(qA0, qA1, qA2, qA3, roff);
        avA = *(const f32x4*)(f1t + i4);

        #pragma unroll
        for (int cc = 0; cc < CC; cc += 2) {
            // even channel cc: prefetch cc+1 into B, compute A
            DS_READ4(qB0, qB1, qB2, qB3, roff + (unsigned)((cc + 1) * ROWB));
            avB = *(const f32x4*)(f1t + (size_t)(cc + 1) * chw + i4);
            WAITQ(qA0, qA1, qA2, qA3, 4);   // qA ready; qB's 4 in flight
            FMA_CH(avA, qA0, qA1, qA2, qA3);

            // odd channel cc+1: prefetch cc+2 into A (if any), compute B
            if (cc + 2 < CC) {
                DS_READ4(qA0, qA1, qA2, qA3, roff + (unsigned)((cc + 2) * ROWB));
                avA = *(const f32x4*)(f1t + (size_t)(cc + 2) * chw + i4);
                WAITQ(qB0, qB1, qB2, qB3, 4);
            } else {
                WAITQ(qB0, qB1, qB2, qB3, 0);   // drain last channel's reads
            }
            FMA_CH(avB, qB0, qB1, qB2, qB3);
        }

        // one barrier per tile: waits vmcnt(0) (staging DMA landed) and
        // gates buffer swap (all waves done reading buf[pb]).
        __syncthreads();
    }

    // ---- epilogue: leaky_relu + float4 stores (contiguous per wave) ----
    #pragma unroll
    for (int dr = 0; dr < TD; ++dr) {
        int d = j * TD + dr;
        float vx[4];
        #pragma unroll
        for (int xr = 0; xr < 4; ++xr) {
            float t = acc[xr][dr];
            vx[xr] = t >= 0.f ? t : 0.1f * t;
        }
        float4 v = make_float4(vx[0], vx[1], vx[2], vx[3]);
        *(float4*)(out + (((size_t)(b * ND + d) * Hn + y) * Wn + i * 4)) = v;
    }
}

extern "C" void kernel_launch(void* const* d_in, const int* in_sizes, int n_in,
                              void* d_out, int out_size, void* d_ws, size_t ws_size,
                              hipStream_t stream) {
    const float* feat1 = (const float*)d_in[0];
    const float* feat2 = (const float*)d_in[1];
    float* out = (float*)d_out;
    dim3 grid(Hn, Bn);   // blockIdx.x = y, blockIdx.y = b
    dim3 block(256);
    corr1d_kernel<<<grid, block, 0, stream>>>(feat1, feat2, out);
}

// Round 9
// 287.386 us; speedup vs baseline: 2.1582x; 1.0141x over previous
//
#include <hip/hip_runtime.h>
#include <stdint.h>

// Correlation1dCost: out[b,d,y,x] = leaky_relu_0.1( sum_c f1[b,c,y,x]*f2[b,c,y,x+d-47] )
// B=8, C=128, H=128, W=256, ND=48. Zero contribution where x+d-47 < 0.
//
// R13: kill the in-loop vmcnt chain. R12 (113.6us, VGPR=128) still had
// VALUBusy 30%: vmcnt is IN-ORDER, so the compiler's vmcnt(N) before each
// f1 (av) use also waited on the tile-top global_load_lds DMAs (~900cy HBM)
// -- every tile start stalled all waves right after the barrier. R13 stages
// f1 in LDS via the same DMA: the compute loop has ZERO vmem consumers, so
// the DMA overlaps the whole compute phase and is drained by the end-of-tile
// barrier only. Per channel: 5 counted LDS reads (4 f2-window + 1 f1),
// lgkmcnt(5) double-buffered pipeline, deterministic latency.
// CC=8 keeps LDS at 35840 B -> 4 blocks/CU (16 waves). 16 tiles, 1 barrier
// per tile. Register audit: acc 48 + q 32 + av 8 + addr ~15 = ~105 < 128.

typedef float f32x4 __attribute__((ext_vector_type(4)));

#define Bn 8
#define Cn 128
#define Hn 128
#define Wn 256
#define ND 48
#define F2Q 76             // float4s per f2 row: 12 pad + 64 data
#define ROWB (F2Q * 16)    // 1216 B per f2 channel row
#define CC 8               // channels staged per tile
#define NIT (Cn / CC)      // 16 tiles
#define TD 12              // d's per thread
#define F2B (CC * ROWB)    // 9728 B per f2 buffer
#define F1RB 1024          // f1 row bytes in LDS (64 quads, no pad)
#define F1B (CC * F1RB)    // 8192 B per f1 buffer
#define F1OFF (2 * F2B)    // f1 region starts after both f2 buffers
#define SMEMB (2 * F2B + 2 * F1B)   // 35840 B -> 4 blocks/CU

__device__ __forceinline__ unsigned lds_off(const void* p) {
    return (unsigned)(uintptr_t)p;
}

// 4 contiguous b128 reads, NO waitcnt, NO memory clobber.
#define DS_READ4(q0, q1, q2, q3, off)                                   \
    asm volatile("ds_read_b128 %0, %4\n\t"                              \
                 "ds_read_b128 %1, %4 offset:16\n\t"                    \
                 "ds_read_b128 %2, %4 offset:32\n\t"                    \
                 "ds_read_b128 %3, %4 offset:48"                        \
                 : "=&v"(q0), "=&v"(q1), "=&v"(q2), "=&v"(q3)           \
                 : "v"(off))

// single b128 read for the f1 fragment
#define AV_READ(a, off)                                                 \
    asm volatile("ds_read_b128 %0, %1" : "=&v"(a) : "v"(off))

// Counted wait tied to ALL 5 registers it guards (4 q + av).
#define WAIT5(q0, q1, q2, q3, a, n)                                     \
    asm volatile("s_waitcnt lgkmcnt(" #n ")"                            \
                 : "+v"(q0), "+v"(q1), "+v"(q2), "+v"(q3), "+v"(a))

__device__ __forceinline__ void lds_write_b128(unsigned off, f32x4 v) {
    asm volatile("ds_write_b128 %0, %1" :: "v"(off), "v"(v) : "memory");
}

// Direct HBM->LDS DMA, 16B per lane; dest = wave-uniform base + lane*16.
__device__ __forceinline__ void gload_lds16(const float* g, char* lds) {
    __builtin_amdgcn_global_load_lds(
        (const __attribute__((address_space(1))) void*)g,
        (__attribute__((address_space(3))) void*)lds,
        16, 0, 0);
}

// 48 FMAs for one channel. qq[] has only compile-time indices.
#define FMA_CH(av, p0, p1, p2, p3)                                      \
    do {                                                                \
        const float a0 = (av)[0], a1 = (av)[1], a2 = (av)[2], a3 = (av)[3]; \
        float qq[16] = {(p0)[0], (p0)[1], (p0)[2], (p0)[3],             \
                        (p1)[0], (p1)[1], (p1)[2], (p1)[3],             \
                        (p2)[0], (p2)[1], (p2)[2], (p2)[3],             \
                        (p3)[0], (p3)[1], (p3)[2], (p3)[3]};            \
        _Pragma("unroll")                                               \
        for (int dr = 0; dr < TD; ++dr) {                               \
            acc[0][dr] += a0 * qq[dr + 1];                              \
            acc[1][dr] += a1 * qq[dr + 2];                              \
            acc[2][dr] += a2 * qq[dr + 3];                              \
            acc[3][dr] += a3 * qq[dr + 4];                              \
        }                                                               \
    } while (0)

__global__ __launch_bounds__(256)
__attribute__((amdgpu_waves_per_eu(2, 4)))
void corr1d_kernel(const float* __restrict__ f1,
                   const float* __restrict__ f2,
                   float* __restrict__ out)
{
    __shared__ f32x4 smem[SMEMB / 16];   // 35840 B

    const int y   = blockIdx.x;      // 0..127
    const int b   = blockIdx.y;      // 0..7
    const int tid = threadIdx.x;
    const int i   = tid & 63;        // x-group: x = 4*i .. 4*i+3
    const int j   = tid >> 6;        // d-group: d = 12*j .. 12*j+11

    char* s2c = (char*)&smem[0];
    const unsigned s2b   = lds_off(s2c);
    const unsigned offq0 = s2b + (unsigned)((i + 3 * j) * 16);  // f2 window
    const unsigned aoff0 = s2b + F1OFF + (unsigned)(i * 16);    // f1 fragment

    const size_t chw = (size_t)Hn * Wn;
    const float* f1base = f1 + ((size_t)b * Cn * Hn + y) * Wn;
    const float* f2base = f2 + ((size_t)b * Cn * Hn + y) * Wn;

    const int sp = tid & 63;         // lane id; data quad sp of each row

    // ---- zero the always-zero pad region of both f2 buffers once ----
    if (tid < 192) {
        f32x4 z = {0.f, 0.f, 0.f, 0.f};
        const int buf = tid / 96, rem = tid % 96;
        const int row = rem / 12, q = rem % 12;
        lds_write_b128(s2b + (unsigned)(buf * F2B + (row * F2Q + q) * 16), z);
    }

    float acc[4][TD];
    #pragma unroll
    for (int xr = 0; xr < 4; ++xr)
        #pragma unroll
        for (int dr = 0; dr < TD; ++dr) acc[xr][dr] = 0.f;

    // ---- stage tile 0 (f2 + f1) into buffer 0 via async DMA ----
    #pragma unroll
    for (int t = 0; t < 2; ++t) {
        const int r = j + 4 * t;     // wave-uniform row, covers 0..7
        gload_lds16(f2base + (size_t)r * chw + sp * 4,
                    s2c + (size_t)((r * F2Q + 12 + sp) * 16));
        gload_lds16(f1base + (size_t)r * chw + sp * 4,
                    s2c + F1OFF + (size_t)(r * F1RB + sp * 16));
    }
    __syncthreads();                 // drains vmcnt(0): tile 0 resident

    for (int it = 0; it < NIT; ++it) {
        const unsigned pb2 = (unsigned)(it & 1) * F2B;   // f2 read buffer
        const unsigned pb1 = (unsigned)(it & 1) * F1B;   // f1 read buffer

        // issue next tile's DMA now; overlaps the entire compute phase and
        // is drained only by the end-of-tile barrier. No vmem consumer
        // exists in the compute loop, so nothing waits on these early.
        if (it + 1 < NIT) {
            const float* f2t = f2base + (size_t)((it + 1) * CC) * chw;
            const float* f1t = f1base + (size_t)((it + 1) * CC) * chw;
            #pragma unroll
            for (int t = 0; t < 2; ++t) {
                const int r = j + 4 * t;
                gload_lds16(f2t + (size_t)r * chw + sp * 4,
                            s2c + (F2B - pb2) + (size_t)((r * F2Q + 12 + sp) * 16));
                gload_lds16(f1t + (size_t)r * chw + sp * 4,
                            s2c + F1OFF + (F1B - pb1) + (size_t)(r * F1RB + sp * 16));
            }
        }

        // ---- compute 8 channels, all operands from LDS, reads pipelined
        //      1 channel deep (5 reads/ch), counted lgkmcnt(5) waits ----
        const unsigned roff = offq0 + pb2;
        const unsigned aoff = aoff0 + pb1;

        f32x4 qA0, qA1, qA2, qA3, qB0, qB1, qB2, qB3;
        f32x4 avA, avB;
        DS_READ4(qA0, qA1, qA2, qA3, roff);
        AV_READ(avA, aoff);

        #pragma unroll
        for (int cc = 0; cc < CC; cc += 2) {
            // even channel cc: prefetch cc+1 into B, compute A
            DS_READ4(qB0, qB1, qB2, qB3, roff + (unsigned)((cc + 1) * ROWB));
            AV_READ(avB, aoff + (unsigned)((cc + 1) * F1RB));
            WAIT5(qA0, qA1, qA2, qA3, avA, 5);   // A's 5 done; B's 5 in flight
            FMA_CH(avA, qA0, qA1, qA2, qA3);

            // odd channel cc+1: prefetch cc+2 into A (if any), compute B
            if (cc + 2 < CC) {
                DS_READ4(qA0, qA1, qA2, qA3, roff + (unsigned)((cc + 2) * ROWB));
                AV_READ(avA, aoff + (unsigned)((cc + 2) * F1RB));
                WAIT5(qB0, qB1, qB2, qB3, avB, 5);
            } else {
                WAIT5(qB0, qB1, qB2, qB3, avB, 0);   // drain tile's reads
            }
            FMA_CH(avB, qB0, qB1, qB2, qB3);
        }

        // one barrier per tile: drains staging DMA (vmcnt 0) and gates the
        // buffer swap (all waves done reading pb2/pb1).
        __syncthreads();
    }

    // ---- epilogue: leaky_relu + float4 stores (contiguous per wave) ----
    #pragma unroll
    for (int dr = 0; dr < TD; ++dr) {
        int d = j * TD + dr;
        float vx[4];
        #pragma unroll
        for (int xr = 0; xr < 4; ++xr) {
            float t = acc[xr][dr];
            vx[xr] = t >= 0.f ? t : 0.1f * t;
        }
        float4 v = make_float4(vx[0], vx[1], vx[2], vx[3]);
        *(float4*)(out + (((size_t)(b * ND + d) * Hn + y) * Wn + i * 4)) = v;
    }
}

extern "C" void kernel_launch(void* const* d_in, const int* in_sizes, int n_in,
                              void* d_out, int out_size, void* d_ws, size_t ws_size,
                              hipStream_t stream) {
    const float* feat1 = (const float*)d_in[0];
    const float* feat2 = (const float*)d_in[1];
    float* out = (float*)d_out;
    dim3 grid(Hn, Bn);   // blockIdx.x = y, blockIdx.y = b
    dim3 block(256);
    corr1d_kernel<<<grid, block, 0, stream>>>(feat1, feat2, out);
}